// Round 11
// baseline (102.609 us; speedup 1.0000x reference)
//
#include <hip/hip_runtime.h>
#include <hip/hip_bf16.h>
#include <cstdint>

#define N_NODES 8192
#define F_IN    512
#define D_O     64
#define H_N     8
#define NOUT    512   // H_N * D_O
#define MAXD    128   // max supported degree (mean ~33.8, sigma 5.7 -> 16 sigma)

#define BM 64
#define BN 128
#define BK 64

typedef __attribute__((ext_vector_type(8))) short short8;
typedef __attribute__((ext_vector_type(4))) float f32x4;

static __device__ __forceinline__ ushort f2bf(float f) {
  union { float f; uint32_t u; } v; v.f = f;
  uint32_t r = v.u + 0x7FFFu + ((v.u >> 16) & 1u);  // RNE
  return (ushort)(r >> 16);
}
static __device__ __forceinline__ float bf2f(ushort u) {
  union { uint32_t u; float f; } v; v.u = ((uint32_t)u) << 16;
  return v.f;
}

// ---------------------------------------------------------------------------
// Kernel 0: blocks [0,2048): xb = bf16(x)   (grid-stride float4)
//           blocks [2048,2112): Wt[h][d][k] = bf16(W[h][k][d]) via LDS tile
// ---------------------------------------------------------------------------
__global__ __launch_bounds__(256) void convert(const float* __restrict__ x,
                                               const float* __restrict__ W,
                                               ushort* __restrict__ xb,
                                               ushort* __restrict__ Wt) {
  __shared__ float Ws[64][65];
  const int b = blockIdx.x, t = threadIdx.x;
  if (b < 2048) {
    const int gid = b * 256 + t;
    #pragma unroll
    for (int it = 0; it < 2; ++it) {
      const int q = gid + it * 524288;           // 2*524288 = 1,048,576 float4s
      const float4 v = ((const float4*)x)[q];
      ushort4 u;
      u.x = f2bf(v.x); u.y = f2bf(v.y); u.z = f2bf(v.z); u.w = f2bf(v.w);
      ((ushort4*)xb)[q] = u;
    }
  } else {
    const int bb = b - 2048;                     // 64 blocks = 8 heads x 8 k-tiles
    const int h = bb >> 3, kt = bb & 7;
    const int d = t & 63, krg = (t >> 6) * 16;
    const float* src = &W[((size_t)h * F_IN + kt * 64 + krg) * D_O + d];
    #pragma unroll
    for (int q = 0; q < 16; ++q)
      Ws[krg + q][d] = src[(size_t)q * D_O];     // coalesced over d
    __syncthreads();
    const int d0 = t >> 2, kq = (t & 3) * 16;
    ushort* dst = &Wt[(size_t)h * D_O * F_IN + (size_t)d0 * F_IN + kt * 64 + kq];
    #pragma unroll
    for (int q = 0; q < 16; ++q)
      dst[q] = f2bf(Ws[kq + q][d0]);             // coalesced over k
  }
}

// ---------------------------------------------------------------------------
// Kernel 1 (fused): blocks [0,512): GEMM tiles (dispatched first -> ~2/CU,
//   MFMA work hides under scan's HBM stalls); blocks [512,8704): adj-row scan
//   writing CSR (deg_g, nbr_g). The two roles are data-independent.
// ---------------------------------------------------------------------------
__global__ __launch_bounds__(256) void scan_gemm(const uint32_t* __restrict__ adj,
                                                 const ushort* __restrict__ xb,
                                                 const ushort* __restrict__ Wt,
                                                 const float* __restrict__ a1,
                                                 const float* __restrict__ a2,
                                                 ushort* __restrict__ Whb,
                                                 float* __restrict__ f1,
                                                 float* __restrict__ f2,
                                                 int* __restrict__ nbr_g,
                                                 int* __restrict__ deg_g) {
  __shared__ ushort As[BM][BK + 8];
  __shared__ ushort Bs[BN][BK + 8];
  __shared__ int wsum[4];

  const int id   = blockIdx.x;
  const int tid  = threadIdx.x;
  const int lane = tid & 63;
  const int wv   = tid >> 6;

  if (id < 512) {
    // ---------------- GEMM role ----------------
    const int wr = wv >> 1, wc = wv & 1;
    const int r0 = (id >> 2) * BM;
    const int c0 = (id & 3) * BN;
    const int lm = lane & 15;
    const int lg = lane >> 4;

    f32x4 acc[2][4];
    #pragma unroll
    for (int m2 = 0; m2 < 2; ++m2)
      #pragma unroll
      for (int n2 = 0; n2 < 4; ++n2)
        acc[m2][n2] = (f32x4){0.f, 0.f, 0.f, 0.f};

    for (int k0 = 0; k0 < F_IN; k0 += BK) {
      __syncthreads();
      #pragma unroll
      for (int p = 0; p < 2; ++p) {
        const int e = p * 256 + tid;
        const int row = e >> 3, ck = (e & 7) * 8;
        *(short8*)&As[row][ck] = *(const short8*)&xb[(size_t)(r0 + row) * F_IN + k0 + ck];
      }
      #pragma unroll
      for (int p = 0; p < 4; ++p) {
        const int e = p * 256 + tid;
        const int row = e >> 3, ck = (e & 7) * 8;
        *(short8*)&Bs[row][ck] = *(const short8*)&Wt[(size_t)(c0 + row) * F_IN + k0 + ck];
      }
      __syncthreads();

      #pragma unroll
      for (int kk = 0; kk < 2; ++kk) {
        const int koff = kk * 32 + lg * 8;
        short8 af[2], bf[4];
        #pragma unroll
        for (int m2 = 0; m2 < 2; ++m2)
          af[m2] = *(const short8*)&As[wr * 32 + m2 * 16 + lm][koff];
        #pragma unroll
        for (int n2 = 0; n2 < 4; ++n2)
          bf[n2] = *(const short8*)&Bs[wc * 64 + n2 * 16 + lm][koff];
        #pragma unroll
        for (int m2 = 0; m2 < 2; ++m2)
          #pragma unroll
          for (int n2 = 0; n2 < 4; ++n2)
            acc[m2][n2] = __builtin_amdgcn_mfma_f32_16x16x32_bf16(af[m2], bf[n2], acc[m2][n2], 0, 0, 0);
      }
    }

    // epilogue: Whb write + fused f1/f2
    const int head = (c0 >> 6) + wc;
    float a1v[4], a2v[4];
    #pragma unroll
    for (int n2 = 0; n2 < 4; ++n2) {
      a1v[n2] = a1[head * D_O + n2 * 16 + lm];
      a2v[n2] = a2[head * D_O + n2 * 16 + lm];
    }
    #pragma unroll
    for (int m2 = 0; m2 < 2; ++m2) {
      #pragma unroll
      for (int r = 0; r < 4; ++r) {
        const int row = r0 + wr * 32 + m2 * 16 + lg * 4 + r;
        float p1 = 0.f, p2 = 0.f;
        #pragma unroll
        for (int n2 = 0; n2 < 4; ++n2) {
          const float v = acc[m2][n2][r];
          p1 += v * a1v[n2];
          p2 += v * a2v[n2];
          Whb[(size_t)row * NOUT + c0 + wc * 64 + n2 * 16 + lm] = f2bf(v);
        }
        #pragma unroll
        for (int o = 1; o < 16; o <<= 1) {
          p1 += __shfl_xor(p1, o);
          p2 += __shfl_xor(p2, o);
        }
        if (lm == 0) {
          f1[(size_t)row * H_N + head] = p1;
          f2[(size_t)row * H_N + head] = p2;
        }
      }
    }
  } else {
    // ---------------- SCAN role ----------------
    const int i = id - 512;
    const uint32_t* arow = adj + (size_t)i * N_NODES;
    uint32_t bits = 0;
    #pragma unroll
    for (int u = 0; u < 8; ++u) {
      const uint4 a = *(const uint4*)&arow[(u * 256 + tid) * 4];
      if (a.x) bits |= 1u << (u * 4 + 0);
      if (a.y) bits |= 1u << (u * 4 + 1);
      if (a.z) bits |= 1u << (u * 4 + 2);
      if (a.w) bits |= 1u << (u * 4 + 3);
    }
    const int cnt = __popc(bits);
    int v = cnt;
    #pragma unroll
    for (int o = 1; o < 64; o <<= 1) {
      int u = __shfl_up(v, o);
      if (lane >= o) v += u;
    }
    if (lane == 63) wsum[wv] = v;
    __syncthreads();
    int base = 0, total = 0;
    #pragma unroll
    for (int ww = 0; ww < 4; ++ww) {
      int s = wsum[ww];
      if (ww < wv) base += s;
      total += s;
    }
    int off = base + v - cnt;
    #pragma unroll
    for (int u = 0; u < 8; ++u)
      #pragma unroll
      for (int bq = 0; bq < 4; ++bq)
        if (bits & (1u << (u * 4 + bq))) {
          if (off < MAXD) nbr_g[(size_t)i * MAXD + off] = (u * 256 + tid) * 4 + bq;
          ++off;
        }
    if (tid == 0) deg_g[i] = min(total, MAXD);
  }
}

// ---------------------------------------------------------------------------
// Kernel 2: attention B-D only (CSR input). 128-thread (2-wave) block per row.
// B) logits  C) softmax (wave w: heads 4w..4w+3)
// D) thread t accumulates cols [4t,4t+4) via ushort4 gather, float4 store.
// ---------------------------------------------------------------------------
__global__ __launch_bounds__(128) void gat_attn(const int* __restrict__ nbr_g,
                                                const int* __restrict__ deg_g,
                                                const ushort* __restrict__ Whb,
                                                const float* __restrict__ f1,
                                                const float* __restrict__ f2,
                                                float* __restrict__ out) {
  const int i    = blockIdx.x;
  const int tid  = threadIdx.x;   // 0..127
  const int lane = tid & 63;
  const int w    = tid >> 6;      // 0..1

  __shared__ int   nbr[MAXD];
  __shared__ float p[MAXD][9];
  __shared__ float f1s[8], invs[8];

  const int deg = deg_g[i];
  if (tid < 8) f1s[tid] = f1[(size_t)i * H_N + tid];
  nbr[tid] = nbr_g[(size_t)i * MAXD + tid];   // 128 threads cover MAXD exactly
  __syncthreads();

  // --- B: logits ---------------------------------------------------------
  for (int idx = tid; idx < deg * H_N; idx += 128) {
    const int n = idx >> 3, h = idx & 7;
    const int j = nbr[n];
    float l = f1s[h] + f2[(size_t)j * H_N + h];
    l = l > 0.f ? l : 0.2f * l;
    p[n][h] = l;
  }
  __syncthreads();

  // --- C: softmax (wave w handles heads 4w..4w+3) ------------------------
  #pragma unroll
  for (int hh = 0; hh < 4; ++hh) {
    const int h = w * 4 + hh;
    float m = -3.0e38f;
    for (int n = lane; n < deg; n += 64) m = fmaxf(m, p[n][h]);
    #pragma unroll
    for (int o = 32; o; o >>= 1) m = fmaxf(m, __shfl_xor(m, o));
    float s = 0.f;
    for (int n = lane; n < deg; n += 64) {
      const float e = __expf(p[n][h] - m);
      p[n][h] = e;
      s += e;
    }
    #pragma unroll
    for (int o = 32; o; o >>= 1) s += __shfl_xor(s, o);
    if (lane == 0) invs[h] = 1.0f / s;
  }
  __syncthreads();

  // --- D: weighted accumulation (4 cols per thread, ushort4 gather) ------
  const int h = tid >> 4;                        // (4*tid)/64
  float a0 = 0.f, a1c = 0.f, a2c = 0.f, a3 = 0.f;
  #pragma unroll 8
  for (int n = 0; n < deg; ++n) {
    const float pv = p[n][h];
    const ushort4 u = *(const ushort4*)&Whb[(size_t)nbr[n] * NOUT + tid * 4];
    a0  += pv * bf2f(u.x);
    a1c += pv * bf2f(u.y);
    a2c += pv * bf2f(u.z);
    a3  += pv * bf2f(u.w);
  }
  const float inv = invs[h];
  float4 o4;
  o4.x = a0 * inv; o4.y = a1c * inv; o4.z = a2c * inv; o4.w = a3 * inv;
  *(float4*)&out[(size_t)i * NOUT + tid * 4] = o4;
}

extern "C" void kernel_launch(void* const* d_in, const int* in_sizes, int n_in,
                              void* d_out, int out_size, void* d_ws, size_t ws_size,
                              hipStream_t stream) {
  const float* x   = (const float*)d_in[0];
  const float* adj = (const float*)d_in[1];
  const float* W   = (const float*)d_in[2];
  const float* a1  = (const float*)d_in[3];
  const float* a2  = (const float*)d_in[4];
  float* out = (float*)d_out;

  ushort* Whb = (ushort*)d_ws;                          // 4M bf16 = 8 MB
  ushort* xb  = Whb + (size_t)N_NODES * NOUT;           // 4M bf16 = 8 MB
  ushort* Wt  = xb + (size_t)N_NODES * F_IN;            // 256K bf16 = 0.5 MB
  float*  f1  = (float*)(Wt + (size_t)H_N * D_O * F_IN);
  float*  f2  = f1 + (size_t)N_NODES * H_N;
  int*    nbr_g = (int*)(f2 + (size_t)N_NODES * H_N);   // 8192*128*4 = 4 MB
  int*    deg_g = nbr_g + (size_t)N_NODES * MAXD;       // 32 KB

  hipLaunchKernelGGL(convert, dim3(2112), dim3(256), 0, stream, x, W, xb, Wt);
  hipLaunchKernelGGL(scan_gemm, dim3(512 + N_NODES), dim3(256), 0, stream,
                     (const uint32_t*)adj, xb, Wt, a1, a2, Whb, f1, f2, nbr_g, deg_g);
  hipLaunchKernelGGL(gat_attn, dim3(N_NODES), dim3(128), 0, stream,
                     nbr_g, deg_g, Whb, f1, f2, out);
}

// Round 12
// 94.063 us; speedup vs baseline: 1.0908x; 1.0908x over previous
//
#include <hip/hip_runtime.h>
#include <hip/hip_bf16.h>
#include <cstdint>

#define N_NODES 8192
#define F_IN    512
#define D_O     64
#define H_N     8
#define NOUT    512   // H_N * D_O
#define MAXD    128   // max supported degree (mean ~33.8, sigma 5.7 -> 16 sigma)

#define BM 64
#define BN 128
#define BK 64

typedef __attribute__((ext_vector_type(8))) short short8;
typedef __attribute__((ext_vector_type(4))) float f32x4;

static __device__ __forceinline__ ushort f2bf(float f) {
  union { float f; uint32_t u; } v; v.f = f;
  uint32_t r = v.u + 0x7FFFu + ((v.u >> 16) & 1u);  // RNE
  return (ushort)(r >> 16);
}
static __device__ __forceinline__ float bf2f(ushort u) {
  union { uint32_t u; float f; } v; v.u = ((uint32_t)u) << 16;
  return v.f;
}

// ---------------------------------------------------------------------------
// Kernel 0: blocks [0,2048): xb = bf16(x)   (grid-stride float4)
//           blocks [2048,2112): Wt[h][d][k] = bf16(W[h][k][d]) via LDS tile
// ---------------------------------------------------------------------------
__global__ __launch_bounds__(256) void convert(const float* __restrict__ x,
                                               const float* __restrict__ W,
                                               ushort* __restrict__ xb,
                                               ushort* __restrict__ Wt) {
  __shared__ float Ws[64][65];
  const int b = blockIdx.x, t = threadIdx.x;
  if (b < 2048) {
    const int gid = b * 256 + t;
    #pragma unroll
    for (int it = 0; it < 2; ++it) {
      const int q = gid + it * 524288;           // 2*524288 = 1,048,576 float4s
      const float4 v = ((const float4*)x)[q];
      ushort4 u;
      u.x = f2bf(v.x); u.y = f2bf(v.y); u.z = f2bf(v.z); u.w = f2bf(v.w);
      ((ushort4*)xb)[q] = u;
    }
  } else {
    const int bb = b - 2048;                     // 64 blocks = 8 heads x 8 k-tiles
    const int h = bb >> 3, kt = bb & 7;
    const int d = t & 63, krg = (t >> 6) * 16;
    const float* src = &W[((size_t)h * F_IN + kt * 64 + krg) * D_O + d];
    #pragma unroll
    for (int q = 0; q < 16; ++q)
      Ws[krg + q][d] = src[(size_t)q * D_O];     // coalesced over d
    __syncthreads();
    const int d0 = t >> 2, kq = (t & 3) * 16;
    ushort* dst = &Wt[(size_t)h * D_O * F_IN + (size_t)d0 * F_IN + kt * 64 + kq];
    #pragma unroll
    for (int q = 0; q < 16; ++q)
      dst[q] = f2bf(Ws[kq + q][d0]);             // coalesced over k
  }
}

// ---------------------------------------------------------------------------
// Kernel 1 (fused): blocks [0,512): GEMM tiles; blocks [512,8704): adj-row
// scan writing CSR (deg_g, nbr_g). Data-independent roles.
// ---------------------------------------------------------------------------
__global__ __launch_bounds__(256) void scan_gemm(const uint32_t* __restrict__ adj,
                                                 const ushort* __restrict__ xb,
                                                 const ushort* __restrict__ Wt,
                                                 const float* __restrict__ a1,
                                                 const float* __restrict__ a2,
                                                 ushort* __restrict__ Whb,
                                                 float* __restrict__ f1,
                                                 float* __restrict__ f2,
                                                 int* __restrict__ nbr_g,
                                                 int* __restrict__ deg_g) {
  __shared__ ushort As[BM][BK + 8];
  __shared__ ushort Bs[BN][BK + 8];
  __shared__ int wsum[4];

  const int id   = blockIdx.x;
  const int tid  = threadIdx.x;
  const int lane = tid & 63;
  const int wv   = tid >> 6;

  if (id < 512) {
    // ---------------- GEMM role ----------------
    const int wr = wv >> 1, wc = wv & 1;
    const int r0 = (id >> 2) * BM;
    const int c0 = (id & 3) * BN;
    const int lm = lane & 15;
    const int lg = lane >> 4;

    f32x4 acc[2][4];
    #pragma unroll
    for (int m2 = 0; m2 < 2; ++m2)
      #pragma unroll
      for (int n2 = 0; n2 < 4; ++n2)
        acc[m2][n2] = (f32x4){0.f, 0.f, 0.f, 0.f};

    for (int k0 = 0; k0 < F_IN; k0 += BK) {
      __syncthreads();
      #pragma unroll
      for (int p = 0; p < 2; ++p) {
        const int e = p * 256 + tid;
        const int row = e >> 3, ck = (e & 7) * 8;
        *(short8*)&As[row][ck] = *(const short8*)&xb[(size_t)(r0 + row) * F_IN + k0 + ck];
      }
      #pragma unroll
      for (int p = 0; p < 4; ++p) {
        const int e = p * 256 + tid;
        const int row = e >> 3, ck = (e & 7) * 8;
        *(short8*)&Bs[row][ck] = *(const short8*)&Wt[(size_t)(c0 + row) * F_IN + k0 + ck];
      }
      __syncthreads();

      #pragma unroll
      for (int kk = 0; kk < 2; ++kk) {
        const int koff = kk * 32 + lg * 8;
        short8 af[2], bf[4];
        #pragma unroll
        for (int m2 = 0; m2 < 2; ++m2)
          af[m2] = *(const short8*)&As[wr * 32 + m2 * 16 + lm][koff];
        #pragma unroll
        for (int n2 = 0; n2 < 4; ++n2)
          bf[n2] = *(const short8*)&Bs[wc * 64 + n2 * 16 + lm][koff];
        #pragma unroll
        for (int m2 = 0; m2 < 2; ++m2)
          #pragma unroll
          for (int n2 = 0; n2 < 4; ++n2)
            acc[m2][n2] = __builtin_amdgcn_mfma_f32_16x16x32_bf16(af[m2], bf[n2], acc[m2][n2], 0, 0, 0);
      }
    }

    // epilogue: Whb write + fused f1/f2
    const int head = (c0 >> 6) + wc;
    float a1v[4], a2v[4];
    #pragma unroll
    for (int n2 = 0; n2 < 4; ++n2) {
      a1v[n2] = a1[head * D_O + n2 * 16 + lm];
      a2v[n2] = a2[head * D_O + n2 * 16 + lm];
    }
    #pragma unroll
    for (int m2 = 0; m2 < 2; ++m2) {
      #pragma unroll
      for (int r = 0; r < 4; ++r) {
        const int row = r0 + wr * 32 + m2 * 16 + lg * 4 + r;
        float p1 = 0.f, p2 = 0.f;
        #pragma unroll
        for (int n2 = 0; n2 < 4; ++n2) {
          const float v = acc[m2][n2][r];
          p1 += v * a1v[n2];
          p2 += v * a2v[n2];
          Whb[(size_t)row * NOUT + c0 + wc * 64 + n2 * 16 + lm] = f2bf(v);
        }
        #pragma unroll
        for (int o = 1; o < 16; o <<= 1) {
          p1 += __shfl_xor(p1, o);
          p2 += __shfl_xor(p2, o);
        }
        if (lm == 0) {
          f1[(size_t)row * H_N + head] = p1;
          f2[(size_t)row * H_N + head] = p2;
        }
      }
    }
  } else {
    // ---------------- SCAN role ----------------
    const int i = id - 512;
    const uint32_t* arow = adj + (size_t)i * N_NODES;
    uint32_t bits = 0;
    #pragma unroll
    for (int u = 0; u < 8; ++u) {
      const uint4 a = *(const uint4*)&arow[(u * 256 + tid) * 4];
      if (a.x) bits |= 1u << (u * 4 + 0);
      if (a.y) bits |= 1u << (u * 4 + 1);
      if (a.z) bits |= 1u << (u * 4 + 2);
      if (a.w) bits |= 1u << (u * 4 + 3);
    }
    const int cnt = __popc(bits);
    int v = cnt;
    #pragma unroll
    for (int o = 1; o < 64; o <<= 1) {
      int u = __shfl_up(v, o);
      if (lane >= o) v += u;
    }
    if (lane == 63) wsum[wv] = v;
    __syncthreads();
    int base = 0, total = 0;
    #pragma unroll
    for (int ww = 0; ww < 4; ++ww) {
      int s = wsum[ww];
      if (ww < wv) base += s;
      total += s;
    }
    int off = base + v - cnt;
    #pragma unroll
    for (int u = 0; u < 8; ++u)
      #pragma unroll
      for (int bq = 0; bq < 4; ++bq)
        if (bits & (1u << (u * 4 + bq))) {
          if (off < MAXD) nbr_g[(size_t)i * MAXD + off] = (u * 256 + tid) * 4 + bq;
          ++off;
        }
    if (tid == 0) deg_g[i] = min(total, MAXD);
  }
}

// ---------------------------------------------------------------------------
// Kernel 2: panel attention. Grid = 4 panels x 8192 rows, panel-major so
// co-resident blocks share one 2 MB Whb panel (fits per-XCD L2).
// One wave per block; panel = 128 cols = 2 heads; half-wave per head softmax.
// ---------------------------------------------------------------------------
__global__ __launch_bounds__(64) void gat_panel(const int* __restrict__ nbr_g,
                                                const int* __restrict__ deg_g,
                                                const ushort* __restrict__ Whb,
                                                const float* __restrict__ f1,
                                                const float* __restrict__ f2,
                                                float* __restrict__ out) {
  const int bid = blockIdx.x;
  const int P   = bid >> 13;      // panel 0..3
  const int i   = bid & 8191;     // row
  const int t   = threadIdx.x;    // 0..63

  __shared__ int   nbr[MAXD];
  __shared__ float ff[MAXD][2];
  __shared__ float ps[MAXD][2];
  __shared__ float f1s2[2], invs2[2];

  const int deg = deg_g[i];
  if (t < deg)      nbr[t]      = nbr_g[(size_t)i * MAXD + t];
  if (t + 64 < deg) nbr[t + 64] = nbr_g[(size_t)i * MAXD + t + 64];
  if (t < 2) f1s2[t] = f1[(size_t)i * H_N + 2 * P + t];
  __syncthreads();

  // f2 pair gather (both heads of this panel in one 8-B load)
  for (int n = t; n < deg; n += 64) {
    const float2 v = *(const float2*)&f2[(size_t)nbr[n] * H_N + 2 * P];
    ff[n][0] = v.x; ff[n][1] = v.y;
  }
  __syncthreads();

  // softmax: lanes [0,32) -> head 0, [32,64) -> head 1 (xor offsets <=16 stay in-half)
  {
    const int h = t >> 5;
    const int l = t & 31;
    const float f1v = f1s2[h];
    float m = -3.0e38f;
    for (int n = l; n < deg; n += 32) {
      float e = f1v + ff[n][h];
      e = e > 0.f ? e : 0.2f * e;
      ps[n][h] = e;
      m = fmaxf(m, e);
    }
    #pragma unroll
    for (int o = 16; o; o >>= 1) m = fmaxf(m, __shfl_xor(m, o));
    float s = 0.f;
    for (int n = l; n < deg; n += 32) {
      const float e = __expf(ps[n][h] - m);
      ps[n][h] = e;
      s += e;
    }
    #pragma unroll
    for (int o = 16; o; o >>= 1) s += __shfl_xor(s, o);
    if (l == 0) invs2[h] = 1.0f / s;
  }
  __syncthreads();

  // gather/accumulate: thread t owns panel cols {2t, 2t+1}; head = t>>5
  const int ht      = t >> 5;
  const int colbase = P * 128 + t * 2;
  float a0 = 0.f, a1c = 0.f;
  #pragma unroll 8
  for (int n = 0; n < deg; ++n) {
    const float pv = ps[n][ht];
    const ushort2 u = *(const ushort2*)&Whb[(size_t)nbr[n] * NOUT + colbase];
    a0  += pv * bf2f(u.x);
    a1c += pv * bf2f(u.y);
  }
  const float inv = invs2[ht];
  float2 o2; o2.x = a0 * inv; o2.y = a1c * inv;
  *(float2*)&out[(size_t)i * NOUT + colbase] = o2;
}

extern "C" void kernel_launch(void* const* d_in, const int* in_sizes, int n_in,
                              void* d_out, int out_size, void* d_ws, size_t ws_size,
                              hipStream_t stream) {
  const float* x   = (const float*)d_in[0];
  const float* adj = (const float*)d_in[1];
  const float* W   = (const float*)d_in[2];
  const float* a1  = (const float*)d_in[3];
  const float* a2  = (const float*)d_in[4];
  float* out = (float*)d_out;

  ushort* Whb = (ushort*)d_ws;                          // 4M bf16 = 8 MB
  ushort* xb  = Whb + (size_t)N_NODES * NOUT;           // 4M bf16 = 8 MB
  ushort* Wt  = xb + (size_t)N_NODES * F_IN;            // 256K bf16 = 0.5 MB
  float*  f1  = (float*)(Wt + (size_t)H_N * D_O * F_IN);
  float*  f2  = f1 + (size_t)N_NODES * H_N;
  int*    nbr_g = (int*)(f2 + (size_t)N_NODES * H_N);   // 8192*128*4 = 4 MB
  int*    deg_g = nbr_g + (size_t)N_NODES * MAXD;       // 32 KB

  hipLaunchKernelGGL(convert, dim3(2112), dim3(256), 0, stream, x, W, xb, Wt);
  hipLaunchKernelGGL(scan_gemm, dim3(512 + N_NODES), dim3(256), 0, stream,
                     (const uint32_t*)adj, xb, Wt, a1, a2, Whb, f1, f2, nbr_g, deg_g);
  hipLaunchKernelGGL(gat_panel, dim3(4 * N_NODES), dim3(64), 0, stream,
                     nbr_g, deg_g, Whb, f1, f2, out);
}